// Round 9
// baseline (328.428 us; speedup 1.0000x reference)
//
#include <hip/hip_runtime.h>
#include <hip/hip_bf16.h>

typedef __hip_bfloat16 bf16;
typedef __attribute__((ext_vector_type(8))) short short8;   // 8 bf16 (4 VGPRs)
typedef __attribute__((ext_vector_type(4))) float f32x4;

constexpr int D     = 1024;
constexpr int T     = 2048;
constexpr int BATCH = 2;
constexpr int ROWS  = BATCH * T;   // 4096
constexpr int NH    = 16;
constexpr int DKEY  = 64;
constexpr int QKVN  = 3 * D;       // 3072
constexpr int FFNN  = 4 * D;       // 4096

static __device__ __forceinline__ float b2f(bf16 x) { return __bfloat162float(x); }
static __device__ __forceinline__ bf16  f2b(float x) { return __float2bfloat16(x); }
static __device__ __forceinline__ float fast_exp2(float x) { return __builtin_amdgcn_exp2f(x); }
static __device__ __forceinline__ unsigned short f2bu(float x) {
    return __bfloat16_as_ushort(__float2bfloat16(x));
}
static __device__ __forceinline__ float bits2f(unsigned short u) {
    unsigned int w = (unsigned int)u << 16;
    return __builtin_bit_cast(float, w);
}

// async global->LDS, 16 B per lane. LDS dest is wave-uniform base + lane*16.
static __device__ __forceinline__ void gload_lds16(const bf16* g, unsigned short* l) {
    __builtin_amdgcn_global_load_lds(
        (const __attribute__((address_space(1))) void*)g,
        (__attribute__((address_space(3))) void*)l,
        16, 0, 0);
}

// ---------- fp32 [R][C] -> bf16 [C][R] transpose + downcast ----------
__global__ __launch_bounds__(256) void transpose_cast(const float* __restrict__ in,
                                                      bf16* __restrict__ out,
                                                      int R, int C)
{
    __shared__ float tile[32][33];
    int c0 = blockIdx.x * 32, r0 = blockIdx.y * 32;
    int tx = threadIdx.x & 31, ty = threadIdx.x >> 5;  // 8 rows per pass
#pragma unroll
    for (int i = 0; i < 32; i += 8)
        tile[ty + i][tx] = in[(size_t)(r0 + ty + i) * C + c0 + tx];
    __syncthreads();
#pragma unroll
    for (int i = 0; i < 32; i += 8)
        out[(size_t)(c0 + ty + i) * R + r0 + tx] = f2b(tile[tx][ty + i]);
}

// ---------- LayerNorm: one block per row of 1024, vectorized loads/stores ----------
template <typename TIN>
__global__ __launch_bounds__(256) void ln_kernel(const TIN* __restrict__ X,
                                                 const float* __restrict__ g,
                                                 const float* __restrict__ b,
                                                 bf16* __restrict__ out)
{
    int row = blockIdx.x;
    int tid = threadIdx.x;
    int c0  = tid * 4;              // 4 contiguous elems per thread
    const TIN* xr = X + (size_t)row * D;
    float v[4];
    if constexpr (__is_same(TIN, float)) {
        float4 ld = *(const float4*)(xr + c0);
        v[0] = ld.x; v[1] = ld.y; v[2] = ld.z; v[3] = ld.w;
    } else {
        uint2 raw = *(const uint2*)(xr + c0);
        v[0] = bits2f((unsigned short)(raw.x & 0xffff));
        v[1] = bits2f((unsigned short)(raw.x >> 16));
        v[2] = bits2f((unsigned short)(raw.y & 0xffff));
        v[3] = bits2f((unsigned short)(raw.y >> 16));
    }

    float s1 = v[0] + v[1] + v[2] + v[3];
    float s2 = v[0]*v[0] + v[1]*v[1] + v[2]*v[2] + v[3]*v[3];
#pragma unroll
    for (int off = 32; off; off >>= 1) {
        s1 += __shfl_xor(s1, off);
        s2 += __shfl_xor(s2, off);
    }
    __shared__ float red[8];
    int lane = tid & 63, w = tid >> 6;
    if (lane == 0) { red[w] = s1; red[4 + w] = s2; }
    __syncthreads();
    s1 = red[0] + red[1] + red[2] + red[3];
    s2 = red[4] + red[5] + red[6] + red[7];

    float mu   = s1 * (1.0f / D);
    float var  = s2 * (1.0f / D) - mu * mu;
    float rstd = rsqrtf(var + 1e-5f);

    float4 gv = *(const float4*)(g + c0);
    float4 bv = *(const float4*)(b + c0);
    ushort4 pk;
    pk.x = f2bu((v[0] - mu) * rstd * gv.x + bv.x);
    pk.y = f2bu((v[1] - mu) * rstd * gv.y + bv.y);
    pk.z = f2bu((v[2] - mu) * rstd * gv.z + bv.z);
    pk.w = f2bu((v[3] - mu) * rstd * gv.w + bv.w);
    *(ushort4*)(out + (size_t)row * D + c0) = pk;
}

// ---------- MFMA GEMM (2-buffer, verified): now used for Wo only ----------
template <int BM, int RELU, int RES, int OUTF32, int SPLITZ>
__global__ __launch_bounds__(256) void mfma_gemm(
    const bf16* __restrict__ A, const bf16* __restrict__ Bt,
    const float* __restrict__ bias, const void* __restrict__ resid,
    void* __restrict__ out, float* __restrict__ part,
    int M, int N, int K, int Kstride)
{
    constexpr int MT = BM / 32;
    __shared__ __align__(16) unsigned short As[2][BM * 32];
    __shared__ __align__(16) unsigned short Bs[2][128 * 32];

    int gx = gridDim.x, gy = gridDim.y;
    int lid = (blockIdx.z * gy + blockIdx.y) * gx + blockIdx.x;
    int nwg = gx * gy * gridDim.z;
    int chunk = nwg >> 3;
    int swz = (lid & 7) * chunk + (lid >> 3);
    int bx = swz % gx;
    int by = (swz / gx) % gy;
    int bz = swz / (gx * gy);

    int tid  = threadIdx.x;
    int m0   = by * BM, n0 = bx * 128;
    int lane = tid & 63, wave = tid >> 6;
    int wm = (wave >> 1) * (MT * 16), wn = (wave & 1) * 64;
    int c15 = lane & 15, quad = lane >> 4;

    int koff = 0;
    if constexpr (SPLITZ) koff = bz * K;

    f32x4 acc[MT][4] = {};

    int srow = lane >> 2;
    int scol = (lane & 3) * 8;
    const bf16* abase = A  + (size_t)m0 * Kstride + koff;
    const bf16* bbase = Bt + (size_t)n0 * Kstride + koff;

    auto stage = [&](int buf, int kt) {
        int ko = kt * 32;
#pragma unroll
        for (int j = 0; j < 2; ++j) {
            int r = wave * 32 + j * 16;
            gload_lds16(bbase + (size_t)(r + srow) * Kstride + ko + scol,
                        &Bs[buf][r * 32]);
        }
        if constexpr (BM == 128) {
#pragma unroll
            for (int j = 0; j < 2; ++j) {
                int r = wave * 32 + j * 16;
                gload_lds16(abase + (size_t)(r + srow) * Kstride + ko + scol,
                            &As[buf][r * 32]);
            }
        } else {
            int r = wave * 16;
            gload_lds16(abase + (size_t)(r + srow) * Kstride + ko + scol,
                        &As[buf][r * 32]);
        }
    };

    int nk = K >> 5;
    stage(0, 0);
    __syncthreads();

    for (int kt = 0; kt < nk; ++kt) {
        int buf = kt & 1;
        if (kt + 1 < nk) stage(buf ^ 1, kt + 1);

        short8 af[MT], bfr[4];
#pragma unroll
        for (int t = 0; t < MT; ++t)
            af[t]  = *(const short8*)&As[buf][(wm + t * 16 + c15) * 32 + quad * 8];
#pragma unroll
        for (int t = 0; t < 4; ++t)
            bfr[t] = *(const short8*)&Bs[buf][(wn + t * 16 + c15) * 32 + quad * 8];
#pragma unroll
        for (int mt = 0; mt < MT; ++mt)
#pragma unroll
            for (int nt = 0; nt < 4; ++nt)
                acc[mt][nt] = __builtin_amdgcn_mfma_f32_16x16x32_bf16(
                    af[mt], bfr[nt], acc[mt][nt], 0, 0, 0);

        __syncthreads();
    }

#pragma unroll
    for (int mt = 0; mt < MT; ++mt) {
#pragma unroll
        for (int nt = 0; nt < 4; ++nt) {
            f32x4 v4 = acc[mt][nt];
            int gc = n0 + wn + nt * 16 + c15;
            float bb = bias[gc];
#pragma unroll
            for (int r = 0; r < 4; ++r) {
                int gr = m0 + wm + mt * 16 + quad * 4 + r;
                float v = v4[r] + bb;
                if constexpr (RELU) v = fmaxf(v, 0.0f);
                size_t idx = (size_t)gr * N + gc;
                if constexpr (RES == 1) v += b2f(((const bf16*)resid)[idx]);
                if constexpr (RES == 2) v += ((const float*)resid)[idx];
                if constexpr (OUTF32) ((float*)out)[idx] = v;
                else                  ((bf16*)out)[idx] = f2b(v);
            }
        }
    }
}

// ---------- 8-phase 256x256 GEMM (verified round 7); RELU now a template param ----------
template <int RELU>
__global__ __launch_bounds__(512, 2) void gemm256(
    const bf16* __restrict__ A, const bf16* __restrict__ Bt,
    const float* __restrict__ bias, bf16* __restrict__ out,
    int M, int N, int K)
{
    extern __shared__ unsigned short smem[];
    unsigned short* Abase = smem;           // [2][256*64] = 2 x 32 KiB
    unsigned short* Bbase = smem + 32768;

    int gx = gridDim.x;
    int lid = blockIdx.y * gx + blockIdx.x;
    int nwg = gx * gridDim.y;
    int chunk = nwg >> 3;
    int f = (lid & 7) * chunk + (lid >> 3);
    int bx = f % gx, by = f / gx;

    int tid  = threadIdx.x;
    int m0   = by * 256, n0 = bx * 256;
    int lane = tid & 63, wave = tid >> 6;
    int wm = wave >> 2;
    int wn = (wave & 3) * 64;
    int c15 = lane & 15, quad = lane >> 4;

    int rloc  = lane >> 3;
    int sslot = (lane & 7) ^ (rloc & 7);

    auto stageA = [&](int bufo, int k4, int ko) {
        int r0 = k4 * 64 + wave * 8;
        const bf16* g = A + (size_t)(m0 + r0 + rloc) * K + ko + sslot * 8;
        gload_lds16(g, Abase + bufo + r0 * 64);
    };
    auto stageB = [&](int bufo, int k4, int ko) {
        int r0 = k4 * 64 + wave * 8;
        const bf16* g = Bt + (size_t)(n0 + r0 + rloc) * K + ko + sslot * 8;
        gload_lds16(g, Bbase + bufo + r0 * 64);
    };
    auto ldf = [&](const unsigned short* base, int row, int kq) {
        int slot = kq ^ (row & 7);
        return *(const short8*)&base[row * 64 + slot * 8];
    };

    f32x4 acc[8][4] = {};

    int nt = K >> 6;
#pragma unroll
    for (int k4 = 0; k4 < 4; ++k4) stageA(0, k4, 0);
#pragma unroll
    for (int k4 = 0; k4 < 4; ++k4) stageB(0, k4, 0);

    for (int t = 0; t < nt; ++t) {
        int co = (t & 1) * 16384, no = co ^ 16384;
        bool more = (t + 1 < nt);
        int ko1 = (t + 1) * 64;
        const unsigned short* Ac = Abase + co;
        const unsigned short* Bc = Bbase + co;

        if (more) {
            stageA(no, 0, ko1);
            stageA(no, 1, ko1);
            asm volatile("s_waitcnt vmcnt(2)" ::: "memory");
        } else {
            asm volatile("s_waitcnt vmcnt(0)" ::: "memory");
        }
        __builtin_amdgcn_s_barrier();

#pragma unroll
        for (int p = 0; p < 4; ++p) {
            const int mh = p >> 1, kq0 = (p & 1) * 4 + quad;
            short8 af[4], bf[4];
#pragma unroll
            for (int i = 0; i < 4; ++i)
                af[i] = ldf(Ac, wm * 128 + mh * 64 + i * 16 + c15, kq0);
#pragma unroll
            for (int j = 0; j < 4; ++j)
                bf[j] = ldf(Bc, wn + j * 16 + c15, kq0);
            if (more) {
                if (p == 0) { stageA(no, 2, ko1); stageA(no, 3, ko1); }
                if (p == 1) { stageB(no, 0, ko1); stageB(no, 1, ko1); }
                if (p == 2) { stageB(no, 2, ko1); stageB(no, 3, ko1); }
            }
            __builtin_amdgcn_s_barrier();
            asm volatile("s_waitcnt lgkmcnt(0)" ::: "memory");
            __builtin_amdgcn_sched_barrier(0);
            __builtin_amdgcn_s_setprio(1);
#pragma unroll
            for (int i = 0; i < 4; ++i)
#pragma unroll
                for (int j = 0; j < 4; ++j)
                    acc[mh * 4 + i][j] = __builtin_amdgcn_mfma_f32_16x16x32_bf16(
                        af[i], bf[j], acc[mh * 4 + i][j], 0, 0, 0);
            __builtin_amdgcn_s_setprio(0);
            __builtin_amdgcn_s_barrier();
        }
    }

#pragma unroll
    for (int fr = 0; fr < 8; ++fr) {
#pragma unroll
        for (int j = 0; j < 4; ++j) {
            int gc = n0 + wn + j * 16 + c15;
            float bb = bias[gc];
#pragma unroll
            for (int r = 0; r < 4; ++r) {
                int gr = m0 + wm * 128 + fr * 16 + quad * 4 + r;
                float v = acc[fr][j][r] + bb;
                if constexpr (RELU) v = fmaxf(v, 0.0f);
                out[(size_t)gr * N + gc] = f2b(v);
            }
        }
    }
}

// ---------- 8-phase 256(M)x128(N) split-K GEMM for W2 (verified round 8) ----------
__global__ __launch_bounds__(512, 2) void gemm_w2(
    const bf16* __restrict__ A, const bf16* __restrict__ Bt,
    float* __restrict__ outP, float* __restrict__ part,
    int M, int N, int K, int Kstride)
{
    extern __shared__ unsigned short smem[];
    unsigned short* Abase = smem;           // [2][256*64] = 64 KiB
    unsigned short* Bbase = smem + 32768;   // [2][128*64] = 32 KiB

    int gx = gridDim.x, gy = gridDim.y;
    int lid = (blockIdx.z * gy + blockIdx.y) * gx + blockIdx.x;
    int nwg = gx * gy * gridDim.z;
    int chunk = nwg >> 3;
    int f = (lid & 7) * chunk + (lid >> 3);
    int bx = f % gx;
    int by = (f / gx) % gy;
    int bz = f / (gx * gy);

    int tid  = threadIdx.x;
    int m0   = by * 256, n0 = bx * 128;
    int koff = bz * K;
    int lane = tid & 63, wave = tid >> 6;
    int wm = wave >> 1;
    int wn = (wave & 1) * 64;
    int c15 = lane & 15, quad = lane >> 4;

    int rloc  = lane >> 3;
    int sslot = (lane & 7) ^ (rloc & 7);

    auto stageA = [&](int bufo, int g8, int ko) {
        int r0 = g8 * 64 + wave * 8;
        const bf16* g = A + (size_t)(m0 + r0 + rloc) * Kstride + ko + sslot * 8;
        gload_lds16(g, Abase + bufo + r0 * 64);
    };
    auto stageB = [&](int bufo, int g8, int ko) {
        int r0 = g8 * 64 + wave * 8;
        const bf16* g = Bt + (size_t)(n0 + r0 + rloc) * Kstride + ko + sslot * 8;
        gload_lds16(g, Bbase + bufo + r0 * 64);
    };
    auto ldf = [&](const unsigned short* base, int row, int kq) {
        int slot = kq ^ (row & 7);
        return *(const short8*)&base[row * 64 + slot * 8];
    };

    f32x4 acc[4][4] = {};

    int nt = K >> 6;
#pragma unroll
    for (int g8 = 0; g8 < 4; ++g8) stageA(0, g8, koff);
#pragma unroll
    for (int g8 = 0; g8 < 2; ++g8) stageB(0, g8, koff);

    for (int t = 0; t < nt; ++t) {
        int coA = (t & 1) * 16384, noA = coA ^ 16384;
        int coB = (t & 1) * 8192,  noB = coB ^ 8192;
        bool more = (t + 1 < nt);
        int ko1 = koff + (t + 1) * 64;
        const unsigned short* Ac = Abase + coA;
        const unsigned short* Bc = Bbase + coB;

        if (more) {
            stageA(noA, 0, ko1);
            stageA(noA, 1, ko1);
            asm volatile("s_waitcnt vmcnt(2)" ::: "memory");
        } else {
            asm volatile("s_waitcnt vmcnt(0)" ::: "memory");
        }
        __builtin_amdgcn_s_barrier();

#pragma unroll
        for (int p = 0; p < 2; ++p) {
            const int kq0 = p * 4 + quad;
            short8 af[4], bf[4];
#pragma unroll
            for (int i = 0; i < 4; ++i)
                af[i] = ldf(Ac, wm * 64 + i * 16 + c15, kq0);
#pragma unroll
            for (int j = 0; j < 4; ++j)
                bf[j] = ldf(Bc, wn + j * 16 + c15, kq0);
            if (more) {
                if (p == 0) { stageA(noA, 2, ko1); stageA(noA, 3, ko1); }
                if (p == 1) { stageB(noB, 0, ko1); stageB(noB, 1, ko1); }
            }
            __builtin_amdgcn_s_barrier();
            asm volatile("s_waitcnt lgkmcnt(0)" ::: "memory");
            __builtin_amdgcn_sched_barrier(0);
            __builtin_amdgcn_s_setprio(1);
#pragma unroll
            for (int i = 0; i < 4; ++i)
#pragma unroll
                for (int j = 0; j < 4; ++j)
                    acc[i][j] = __builtin_amdgcn_mfma_f32_16x16x32_bf16(
                        af[i], bf[j], acc[i][j], 0, 0, 0);
            __builtin_amdgcn_s_setprio(0);
            __builtin_amdgcn_s_barrier();
        }
    }

    float* dst = (bz == 0) ? outP : part;
#pragma unroll
    for (int i = 0; i < 4; ++i) {
#pragma unroll
        for (int j = 0; j < 4; ++j) {
            int gc = n0 + wn + j * 16 + c15;
#pragma unroll
            for (int r = 0; r < 4; ++r) {
                int gr = m0 + wm * 64 + i * 16 + quad * 4 + r;
                dst[(size_t)gr * N + gc] = acc[i][j][r];
            }
        }
    }
}

// ---------- W2 reduce: out = out + part + bias + resid(bf16) ----------
__global__ __launch_bounds__(256) void w2_reduce(float* __restrict__ out,
                                                 const float* __restrict__ part,
                                                 const float* __restrict__ bias,
                                                 const bf16* __restrict__ resid)
{
    int i = blockIdx.x * 256 + threadIdx.x;
    int col = (i & (D / 4 - 1)) * 4;
    f32x4 a = ((const f32x4*)out)[i];
    f32x4 p = ((const f32x4*)part)[i];
    float4 bb = *(const float4*)(bias + col);
    uint2 rr = ((const uint2*)resid)[i];
    a[0] += p[0] + bb.x + bits2f((unsigned short)(rr.x & 0xffff));
    a[1] += p[1] + bb.y + bits2f((unsigned short)(rr.x >> 16));
    a[2] += p[2] + bb.z + bits2f((unsigned short)(rr.y & 0xffff));
    a[3] += p[3] + bb.w + bits2f((unsigned short)(rr.y >> 16));
    ((f32x4*)out)[i] = a;
}

// ---------- MFMA flash attention: PAIRED complementary q-tiles ----------
// Round 9: block = 512 threads / 8 waves handles q-tiles (qa=pi, qb=31-pi) of
// the SAME (b,h) -> uniform 33 tile-units/block (no causal tail), shared K/V
// staging (nktb stages instead of nkta+nktb). Waves 0-3 own tile-a row
// quarters, 4-7 tile-b; tile-a waves compute only while kt<nkta (wave-uniform
// branch; barrier count uniform across block). Same verified 2-barrier/tile
// sync structure, T14 reg-prefetch, T5 setprio. Grid 512 blocks (heavy pi=0
// first), LDS 36 KiB.
__global__ __launch_bounds__(512) void flash_attn(const bf16* __restrict__ qkv,
                                                  bf16* __restrict__ ctx)
{
    constexpr int KROW = 72;
    constexpr float CSC = 0.18033688011112042f;  // 0.125 * log2(e)
    constexpr float MSH = 12.0f;                 // fixed exp2-domain shift

    __shared__ __align__(16) unsigned short Qs[128 * KROW];  // aliased by Pt
    __shared__ __align__(16) unsigned short Ks[64 * KROW];   // [key][dk]
    __shared__ __align__(16) unsigned short Vt[64 * KROW];   // [dk][key]
    unsigned short* Pt = Qs;                                 // [128 rows][key]

    int bx = blockIdx.x;
    int bh = bx & 31;
    int pi = bx >> 5;             // 0..15; pi=0 is the heaviest pair
    int h  = bh & 15, b = bh >> 4;
    int qa = pi, qb = 31 - pi;    // qa < qb always
    int q0a = qa * 64, q0b = qb * 64;
    int nkta = qa + 1, nktb = qb + 1;

    int tid = threadIdx.x, lane = tid & 63, w = tid >> 6;  // w 0..7
    int wq = w & 3;               // row-quarter within my tile
    int tb = w >> 2;              // 0 = tile a, 1 = tile b
    int c15 = lane & 15, quad = lane >> 4;

    const bf16* base = qkv + (size_t)b * T * QKVN;

    // --- stage BOTH Q tiles: Qs rows 0..63 = tile a, 64..127 = tile b ---
    {
        int row = tid >> 2, qtr = tid & 3;   // 128 rows x 4 col-quarters
        int grow = (row < 64) ? (q0a + row) : (q0b + row - 64);
        const bf16* src = base + (size_t)grow * QKVN + h * 64 + qtr * 16;
        unsigned short* dst = &Qs[row * KROW + qtr * 16];
        uint4 v0 = *(const uint4*)(src);
        uint4 v1 = *(const uint4*)(src + 8);
        *(uint4*)(dst)     = v0;
        *(uint4*)(dst + 8) = v1;
    }
    __syncthreads();

    // my tile's Q fragment rows (wave-private)
    int qrow_l = tb * 64 + wq * 16 + c15;    // local Pt/Qs row
    short8 qf[2];
#pragma unroll
    for (int s = 0; s < 2; ++s)
        qf[s] = *(const short8*)&Qs[qrow_l * KROW + s * 32 + quad * 8];

    short8 ones;
#pragma unroll
    for (int i = 0; i < 8; ++i) ones[i] = (short)0x3F80;  // bf16 1.0

    f32x4 Ot[4] = {};
    f32x4 lacc  = {};

    int q0m   = tb ? q0b : q0a;
    int nktm  = tb ? nktb : nkta;
    int wqmin = q0m + wq * 16;

    // staging coords (512 threads)
    int key = tid >> 3, seg = tid & 7;            // K: 64 rows x 8 segs of 8
    int keyp = (tid & 31) * 2, dkv = (tid >> 5) * 4;  // V: 2 keys x 4 dk

    // T14 prologue: loads for tile 0
    uint4 kv0;
    uint2 vv0, vv1;
    {
        const bf16* ksrc = base + (size_t)key * QKVN + D + h * 64 + seg * 8;
        kv0 = *(const uint4*)ksrc;
        const bf16* vsrc = base + (size_t)keyp * QKVN + 2 * D + h * 64 + dkv;
        vv0 = *(const uint2*)vsrc;
        vv1 = *(const uint2*)(vsrc + QKVN);
    }

    for (int kt = 0; kt < nktb; ++kt) {
        int k0 = kt * 64;

        __syncthreads();   // previous iteration's Ks/Vt fragment reads complete
        {
            *(uint4*)&Ks[key * KROW + seg * 8] = kv0;
            const unsigned short* lo = (const unsigned short*)&vv0;
            const unsigned short* hi = (const unsigned short*)&vv1;
#pragma unroll
            for (int j = 0; j < 4; ++j) {
                unsigned int pk = (unsigned int)lo[j] | ((unsigned int)hi[j] << 16);
                *(unsigned int*)&Vt[(dkv + j) * KROW + keyp] = pk;  // Vt[dk][key]
            }
        }
        __syncthreads();

        // T14: issue next tile's loads; latency hides under compute
        if (kt + 1 < nktb) {
            int k1 = k0 + 64;
            const bf16* ksrc = base + (size_t)(k1 + key) * QKVN + D + h * 64 + seg * 8;
            kv0 = *(const uint4*)ksrc;
            const bf16* vsrc = base + (size_t)(k1 + keyp) * QKVN + 2 * D + h * 64 + dkv;
            vv0 = *(const uint2*)vsrc;
            vv1 = *(const uint2*)(vsrc + QKVN);
        }

        if (kt < nktm) {   // wave-uniform; tile-a waves idle past their diagonal
            // ---- S^T = K Q^T ----
            f32x4 St[4] = {};
            __builtin_amdgcn_s_setprio(1);
#pragma unroll
            for (int s = 0; s < 2; ++s)
#pragma unroll
                for (int ktm = 0; ktm < 4; ++ktm) {
                    short8 kf = *(const short8*)&Ks[(ktm * 16 + c15) * KROW + s * 32 + quad * 8];
                    St[ktm] = __builtin_amdgcn_mfma_f32_16x16x32_bf16(kf, qf[s], St[ktm], 0, 0, 0);
                }
            __builtin_amdgcn_s_setprio(0);

            // ---- P = exp2(S*CSC - MSH); mask only on my diagonal tile ----
            if (kt == nktm - 1) {
                int q_g = wqmin + c15;
#pragma unroll
                for (int ktm = 0; ktm < 4; ++ktm) {
                    ushort4 pk;
#pragma unroll
                    for (int r = 0; r < 4; ++r) {
                        float p = fast_exp2(fmaf(St[ktm][r], CSC, -MSH));
                        if (k0 + ktm * 16 + quad * 4 + r > q_g) p = 0.0f;
                        ((unsigned short*)&pk)[r] = f2bu(p);
                    }
                    *(ushort4*)&Pt[qrow_l * KROW + ktm * 16 + quad * 4] = pk;
                }
            } else {
#pragma unroll
                for (int ktm = 0; ktm < 4; ++ktm) {
                    ushort4 pk;
#pragma unroll
                    for (int r = 0; r < 4; ++r)
                        ((unsigned short*)&pk)[r] = f2bu(fast_exp2(fmaf(St[ktm][r], CSC, -MSH)));
                    *(ushort4*)&Pt[qrow_l * KROW + ktm * 16 + quad * 4] = pk;
                }
            }

            // ---- O^T += V^T P^T ; l += ones . P^T  (wave-private rows) ----
            __builtin_amdgcn_s_setprio(1);
#pragma unroll
            for (int s = 0; s < 2; ++s) {
                short8 pf = *(const short8*)&Pt[qrow_l * KROW + s * 32 + quad * 8];
                lacc = __builtin_amdgcn_mfma_f32_16x16x32_bf16(ones, pf, lacc, 0, 0, 0);
#pragma unroll
                for (int dt = 0; dt < 4; ++dt) {
                    short8 vf = *(const short8*)&Vt[(dt * 16 + c15) * KROW + s * 32 + quad * 8];
                    Ot[dt] = __builtin_amdgcn_mfma_f32_16x16x32_bf16(vf, pf, Ot[dt], 0, 0, 0);
                }
            }
            __builtin_amdgcn_s_setprio(0);
        }
    }

    // ---- epilogue: ctx[qrow][h*64+dk] = O^T / l ----
    {
        float inv = 1.0f / lacc[0];
        int grow = b * T + q0m + wq * 16 + c15;
        bf16* dst = ctx + (size_t)grow * D + h * 64 + quad * 4;
#pragma unroll
        for (int dt = 0; dt < 4; ++dt) {
            ushort4 pk;
#pragma unroll
            for (int r = 0; r < 4; ++r)
                ((unsigned short*)&pk)[r] = f2bu(Ot[dt][r] * inv);
            *(ushort4*)(dst + dt * 16) = pk;
        }
    }
}

extern "C" void kernel_launch(void* const* d_in, const int* in_sizes, int n_in,
                              void* d_out, int out_size, void* d_ws, size_t ws_size,
                              hipStream_t stream)
{
    const float* X    = (const float*)d_in[0];
    const float* Wqkv = (const float*)d_in[1];
    const float* bqkv = (const float*)d_in[2];
    const float* Wo   = (const float*)d_in[3];
    const float* bo   = (const float*)d_in[4];
    const float* W1   = (const float*)d_in[5];
    const float* b1   = (const float*)d_in[6];
    const float* W2   = (const float*)d_in[7];
    const float* b2   = (const float*)d_in[8];
    const float* ln1g = (const float*)d_in[9];
    const float* ln1b = (const float*)d_in[10];
    const float* ln2g = (const float*)d_in[11];
    const float* ln2b = (const float*)d_in[12];
    float* out = (float*)d_out;

    // Workspace (peak 72 MiB):
    char* ws = (char*)d_ws;
    bf16* Wqkv_t = (bf16*)(ws + 0);          // [3072][1024]  6 MiB
    bf16* Wo_t   = (bf16*)(ws + 6291456);    // [1024][1024]  2 MiB
    bf16* W1_t   = (bf16*)(ws + 8388608);    // [4096][1024]  8 MiB
    bf16* W2_t   = (bf16*)(ws + 16777216);   // [1024][4096]  8 MiB
    bf16* Xn     = (bf16*)(ws + 25165824);   // 8 MiB; reused by X1 after step 2
    bf16* X1     = Xn;
    bf16* qkv    = (bf16*)(ws + 33554432);   // 24 MiB; first 8 MiB reused by Xn2 after attn
    bf16* Xn2    = (bf16*)(ws + 33554432);
    bf16* ctx    = (bf16*)(ws + 58720256);   // 8 MiB
    bf16* mid    = (bf16*)(ws + 41943040);   // 32 MiB; ends at 72 MiB
    float* W2part = (float*)(ws + 0);        // [4096][1024] f32, 16 MiB (weights dead)

    transpose_cast<<<dim3(QKVN / 32, D / 32), 256, 0, stream>>>(Wqkv, Wqkv_t, D, QKVN);
    transpose_cast<<<dim3(D / 32, D / 32), 256, 0, stream>>>(Wo, Wo_t, D, D);
    transpose_cast<<<dim3(FFNN / 32, D / 32), 256, 0, stream>>>(W1, W1_t, D, FFNN);
    transpose_cast<<<dim3(D / 32, FFNN / 32), 256, 0, stream>>>(W2, W2_t, FFNN, D);

    ln_kernel<float><<<ROWS, 256, 0, stream>>>(X, ln1g, ln1b, Xn);
    // QKV: 8-phase 256^2 template (grid 12x16 = 192 blocks, 128 KiB LDS)
    gemm256<0><<<dim3(QKVN / 256, ROWS / 256), 512, 131072, stream>>>(
        Xn, Wqkv_t, bqkv, qkv, ROWS, QKVN, D);
    // attn: paired q-tiles, 512 blocks x 512 threads
    flash_attn<<<512, 512, 0, stream>>>(qkv, ctx);
    mfma_gemm<64, 0, 2, 0, 0><<<dim3(D / 128, ROWS / 64), 256, 0, stream>>>(
        ctx, Wo_t, bo, X, X1, nullptr, ROWS, D, D, D);
    ln_kernel<bf16><<<ROWS, 256, 0, stream>>>(X1, ln2g, ln2b, Xn2);
    // W1: 8-phase 256^2 template — verified round 7
    gemm256<1><<<dim3(FFNN / 256, ROWS / 256), 512, 131072, stream>>>(
        Xn2, W1_t, b1, mid, ROWS, FFNN, D);
    // W2: 8-phase 256x128 split-K=2 — verified round 8
    gemm_w2<<<dim3(D / 128, ROWS / 256, 2), 512, 98304, stream>>>(
        mid, W2_t, out, W2part, ROWS, D, FFNN / 2, FFNN);
    w2_reduce<<<ROWS * D / 4 / 256, 256, 0, stream>>>(out, W2part, b2, X1);
}

// Round 10
// 318.295 us; speedup vs baseline: 1.0318x; 1.0318x over previous
//
#include <hip/hip_runtime.h>
#include <hip/hip_bf16.h>

typedef __hip_bfloat16 bf16;
typedef __attribute__((ext_vector_type(8))) short short8;   // 8 bf16 (4 VGPRs)
typedef __attribute__((ext_vector_type(4))) float f32x4;

constexpr int D     = 1024;
constexpr int T     = 2048;
constexpr int BATCH = 2;
constexpr int ROWS  = BATCH * T;   // 4096
constexpr int NH    = 16;
constexpr int DKEY  = 64;
constexpr int QKVN  = 3 * D;       // 3072
constexpr int FFNN  = 4 * D;       // 4096

static __device__ __forceinline__ float b2f(bf16 x) { return __bfloat162float(x); }
static __device__ __forceinline__ bf16  f2b(float x) { return __float2bfloat16(x); }
static __device__ __forceinline__ float fast_exp2(float x) { return __builtin_amdgcn_exp2f(x); }
static __device__ __forceinline__ unsigned short f2bu(float x) {
    return __bfloat16_as_ushort(__float2bfloat16(x));
}
static __device__ __forceinline__ float bits2f(unsigned short u) {
    unsigned int w = (unsigned int)u << 16;
    return __builtin_bit_cast(float, w);
}

// async global->LDS, 16 B per lane. LDS dest is wave-uniform base + lane*16.
static __device__ __forceinline__ void gload_lds16(const bf16* g, unsigned short* l) {
    __builtin_amdgcn_global_load_lds(
        (const __attribute__((address_space(1))) void*)g,
        (__attribute__((address_space(3))) void*)l,
        16, 0, 0);
}

// ---------- fp32 [R][C] -> bf16 [C][R] transpose + downcast ----------
__global__ __launch_bounds__(256) void transpose_cast(const float* __restrict__ in,
                                                      bf16* __restrict__ out,
                                                      int R, int C)
{
    __shared__ float tile[32][33];
    int c0 = blockIdx.x * 32, r0 = blockIdx.y * 32;
    int tx = threadIdx.x & 31, ty = threadIdx.x >> 5;  // 8 rows per pass
#pragma unroll
    for (int i = 0; i < 32; i += 8)
        tile[ty + i][tx] = in[(size_t)(r0 + ty + i) * C + c0 + tx];
    __syncthreads();
#pragma unroll
    for (int i = 0; i < 32; i += 8)
        out[(size_t)(c0 + ty + i) * R + r0 + tx] = f2b(tile[tx][ty + i]);
}

// ---------- LayerNorm: one block per row of 1024, vectorized loads/stores ----------
template <typename TIN>
__global__ __launch_bounds__(256) void ln_kernel(const TIN* __restrict__ X,
                                                 const float* __restrict__ g,
                                                 const float* __restrict__ b,
                                                 bf16* __restrict__ out)
{
    int row = blockIdx.x;
    int tid = threadIdx.x;
    int c0  = tid * 4;              // 4 contiguous elems per thread
    const TIN* xr = X + (size_t)row * D;
    float v[4];
    if constexpr (__is_same(TIN, float)) {
        float4 ld = *(const float4*)(xr + c0);
        v[0] = ld.x; v[1] = ld.y; v[2] = ld.z; v[3] = ld.w;
    } else {
        uint2 raw = *(const uint2*)(xr + c0);
        v[0] = bits2f((unsigned short)(raw.x & 0xffff));
        v[1] = bits2f((unsigned short)(raw.x >> 16));
        v[2] = bits2f((unsigned short)(raw.y & 0xffff));
        v[3] = bits2f((unsigned short)(raw.y >> 16));
    }

    float s1 = v[0] + v[1] + v[2] + v[3];
    float s2 = v[0]*v[0] + v[1]*v[1] + v[2]*v[2] + v[3]*v[3];
#pragma unroll
    for (int off = 32; off; off >>= 1) {
        s1 += __shfl_xor(s1, off);
        s2 += __shfl_xor(s2, off);
    }
    __shared__ float red[8];
    int lane = tid & 63, w = tid >> 6;
    if (lane == 0) { red[w] = s1; red[4 + w] = s2; }
    __syncthreads();
    s1 = red[0] + red[1] + red[2] + red[3];
    s2 = red[4] + red[5] + red[6] + red[7];

    float mu   = s1 * (1.0f / D);
    float var  = s2 * (1.0f / D) - mu * mu;
    float rstd = rsqrtf(var + 1e-5f);

    float4 gv = *(const float4*)(g + c0);
    float4 bv = *(const float4*)(b + c0);
    ushort4 pk;
    pk.x = f2bu((v[0] - mu) * rstd * gv.x + bv.x);
    pk.y = f2bu((v[1] - mu) * rstd * gv.y + bv.y);
    pk.z = f2bu((v[2] - mu) * rstd * gv.z + bv.z);
    pk.w = f2bu((v[3] - mu) * rstd * gv.w + bv.w);
    *(ushort4*)(out + (size_t)row * D + c0) = pk;
}

// ---------- MFMA GEMM (2-buffer, verified): used for Wo only ----------
template <int BM, int RELU, int RES, int OUTF32, int SPLITZ>
__global__ __launch_bounds__(256) void mfma_gemm(
    const bf16* __restrict__ A, const bf16* __restrict__ Bt,
    const float* __restrict__ bias, const void* __restrict__ resid,
    void* __restrict__ out, float* __restrict__ part,
    int M, int N, int K, int Kstride)
{
    constexpr int MT = BM / 32;
    __shared__ __align__(16) unsigned short As[2][BM * 32];
    __shared__ __align__(16) unsigned short Bs[2][128 * 32];

    int gx = gridDim.x, gy = gridDim.y;
    int lid = (blockIdx.z * gy + blockIdx.y) * gx + blockIdx.x;
    int nwg = gx * gy * gridDim.z;
    int chunk = nwg >> 3;
    int swz = (lid & 7) * chunk + (lid >> 3);
    int bx = swz % gx;
    int by = (swz / gx) % gy;
    int bz = swz / (gx * gy);

    int tid  = threadIdx.x;
    int m0   = by * BM, n0 = bx * 128;
    int lane = tid & 63, wave = tid >> 6;
    int wm = (wave >> 1) * (MT * 16), wn = (wave & 1) * 64;
    int c15 = lane & 15, quad = lane >> 4;

    int koff = 0;
    if constexpr (SPLITZ) koff = bz * K;

    f32x4 acc[MT][4] = {};

    int srow = lane >> 2;
    int scol = (lane & 3) * 8;
    const bf16* abase = A  + (size_t)m0 * Kstride + koff;
    const bf16* bbase = Bt + (size_t)n0 * Kstride + koff;

    auto stage = [&](int buf, int kt) {
        int ko = kt * 32;
#pragma unroll
        for (int j = 0; j < 2; ++j) {
            int r = wave * 32 + j * 16;
            gload_lds16(bbase + (size_t)(r + srow) * Kstride + ko + scol,
                        &Bs[buf][r * 32]);
        }
        if constexpr (BM == 128) {
#pragma unroll
            for (int j = 0; j < 2; ++j) {
                int r = wave * 32 + j * 16;
                gload_lds16(abase + (size_t)(r + srow) * Kstride + ko + scol,
                            &As[buf][r * 32]);
            }
        } else {
            int r = wave * 16;
            gload_lds16(abase + (size_t)(r + srow) * Kstride + ko + scol,
                        &As[buf][r * 32]);
        }
    };

    int nk = K >> 5;
    stage(0, 0);
    __syncthreads();

    for (int kt = 0; kt < nk; ++kt) {
        int buf = kt & 1;
        if (kt + 1 < nk) stage(buf ^ 1, kt + 1);

        short8 af[MT], bfr[4];
#pragma unroll
        for (int t = 0; t < MT; ++t)
            af[t]  = *(const short8*)&As[buf][(wm + t * 16 + c15) * 32 + quad * 8];
#pragma unroll
        for (int t = 0; t < 4; ++t)
            bfr[t] = *(const short8*)&Bs[buf][(wn + t * 16 + c15) * 32 + quad * 8];
#pragma unroll
        for (int mt = 0; mt < MT; ++mt)
#pragma unroll
            for (int nt = 0; nt < 4; ++nt)
                acc[mt][nt] = __builtin_amdgcn_mfma_f32_16x16x32_bf16(
                    af[mt], bfr[nt], acc[mt][nt], 0, 0, 0);

        __syncthreads();
    }

#pragma unroll
    for (int mt = 0; mt < MT; ++mt) {
#pragma unroll
        for (int nt = 0; nt < 4; ++nt) {
            f32x4 v4 = acc[mt][nt];
            int gc = n0 + wn + nt * 16 + c15;
            float bb = bias[gc];
#pragma unroll
            for (int r = 0; r < 4; ++r) {
                int gr = m0 + wm + mt * 16 + quad * 4 + r;
                float v = v4[r] + bb;
                if constexpr (RELU) v = fmaxf(v, 0.0f);
                size_t idx = (size_t)gr * N + gc;
                if constexpr (RES == 1) v += b2f(((const bf16*)resid)[idx]);
                if constexpr (RES == 2) v += ((const float*)resid)[idx];
                if constexpr (OUTF32) ((float*)out)[idx] = v;
                else                  ((bf16*)out)[idx] = f2b(v);
            }
        }
    }
}

// ---------- 8-phase 256(M) x BN(N) GEMM (verified round 7 at BN=256) ----------
// BN=192 variant: 3 n-frags/wave (wn stride 48), 12 MFMA/phase, B-LDS
// 2 x 24 KiB, 7 staged loads/wave/tile (A:4 + B:3). vmcnt(2) at S0 drains the
// previous tile's 7 while keeping the 2 just-issued in flight (in-order retire).
template <int RELU, int BN>
__global__ __launch_bounds__(512, 2) void gemm256(
    const bf16* __restrict__ A, const bf16* __restrict__ Bt,
    const float* __restrict__ bias, bf16* __restrict__ out,
    int M, int N, int K)
{
    constexpr int NF = BN / 64;            // B n-frags per wave (3 or 4)
    extern __shared__ unsigned short smem[];
    unsigned short* Abase = smem;                  // [2][256*64] = 64 KiB
    unsigned short* Bbase = smem + 2 * 256 * 64;   // [2][BN*64]

    int gx = gridDim.x;
    int lid = blockIdx.y * gx + blockIdx.x;
    int nwg = gx * gridDim.y;
    int chunk = nwg >> 3;
    int f = (lid & 7) * chunk + (lid >> 3);
    int bx = f % gx, by = f / gx;

    int tid  = threadIdx.x;
    int m0   = by * 256, n0 = bx * BN;
    int lane = tid & 63, wave = tid >> 6;
    int wm = wave >> 2;
    int wn = (wave & 3) * (BN / 4);
    int c15 = lane & 15, quad = lane >> 4;

    int rloc  = lane >> 3;
    int sslot = (lane & 7) ^ (rloc & 7);

    auto stageA = [&](int bufo, int k4, int ko) {
        int r0 = k4 * 64 + wave * 8;
        const bf16* g = A + (size_t)(m0 + r0 + rloc) * K + ko + sslot * 8;
        gload_lds16(g, Abase + bufo + r0 * 64);
    };
    auto stageB = [&](int bufo, int k4, int ko) {
        int r0 = k4 * 64 + wave * 8;
        const bf16* g = Bt + (size_t)(n0 + r0 + rloc) * K + ko + sslot * 8;
        gload_lds16(g, Bbase + bufo + r0 * 64);
    };
    auto ldf = [&](const unsigned short* base, int row, int kq) {
        int slot = kq ^ (row & 7);
        return *(const short8*)&base[row * 64 + slot * 8];
    };

    f32x4 acc[8][NF] = {};

    int nt = K >> 6;
#pragma unroll
    for (int k4 = 0; k4 < 4; ++k4) stageA(0, k4, 0);
#pragma unroll
    for (int k4 = 0; k4 < NF; ++k4) stageB(0, k4, 0);

    for (int t = 0; t < nt; ++t) {
        int co  = (t & 1) * 16384,     no  = co  ^ 16384;
        int coB = (t & 1) * (BN * 64), noB = coB ^ (BN * 64);
        bool more = (t + 1 < nt);
        int ko1 = (t + 1) * 64;
        const unsigned short* Ac = Abase + co;
        const unsigned short* Bc = Bbase + coB;

        if (more) {
            stageA(no, 0, ko1);
            stageA(no, 1, ko1);
            asm volatile("s_waitcnt vmcnt(2)" ::: "memory");
        } else {
            asm volatile("s_waitcnt vmcnt(0)" ::: "memory");
        }
        __builtin_amdgcn_s_barrier();

#pragma unroll
        for (int p = 0; p < 4; ++p) {
            const int mh = p >> 1, kq0 = (p & 1) * 4 + quad;
            short8 af[4], bf[NF];
#pragma unroll
            for (int i = 0; i < 4; ++i)
                af[i] = ldf(Ac, wm * 128 + mh * 64 + i * 16 + c15, kq0);
#pragma unroll
            for (int j = 0; j < NF; ++j)
                bf[j] = ldf(Bc, wn + j * 16 + c15, kq0);
            if (more) {
                if (p == 0) { stageA(no, 2, ko1); stageA(no, 3, ko1); }
                if (p == 1) { stageB(noB, 0, ko1); stageB(noB, 1, ko1); }
                if (p == 2) {
                    stageB(noB, 2, ko1);
                    if constexpr (NF > 3) stageB(noB, 3, ko1);
                }
            }
            __builtin_amdgcn_s_barrier();
            asm volatile("s_waitcnt lgkmcnt(0)" ::: "memory");
            __builtin_amdgcn_sched_barrier(0);
            __builtin_amdgcn_s_setprio(1);
#pragma unroll
            for (int i = 0; i < 4; ++i)
#pragma unroll
                for (int j = 0; j < NF; ++j)
                    acc[mh * 4 + i][j] = __builtin_amdgcn_mfma_f32_16x16x32_bf16(
                        af[i], bf[j], acc[mh * 4 + i][j], 0, 0, 0);
            __builtin_amdgcn_s_setprio(0);
            __builtin_amdgcn_s_barrier();
        }
    }

#pragma unroll
    for (int fr = 0; fr < 8; ++fr) {
#pragma unroll
        for (int j = 0; j < NF; ++j) {
            int gc = n0 + wn + j * 16 + c15;
            float bb = bias[gc];
#pragma unroll
            for (int r = 0; r < 4; ++r) {
                int gr = m0 + wm * 128 + fr * 16 + quad * 4 + r;
                float v = acc[fr][j][r] + bb;
                if constexpr (RELU) v = fmaxf(v, 0.0f);
                out[(size_t)gr * N + gc] = f2b(v);
            }
        }
    }
}

// ---------- 8-phase 256(M)x128(N) split-K GEMM for W2 (verified round 8) ----------
__global__ __launch_bounds__(512, 2) void gemm_w2(
    const bf16* __restrict__ A, const bf16* __restrict__ Bt,
    float* __restrict__ outP, float* __restrict__ part,
    int M, int N, int K, int Kstride)
{
    extern __shared__ unsigned short smem[];
    unsigned short* Abase = smem;           // [2][256*64] = 64 KiB
    unsigned short* Bbase = smem + 32768;   // [2][128*64] = 32 KiB

    int gx = gridDim.x, gy = gridDim.y;
    int lid = (blockIdx.z * gy + blockIdx.y) * gx + blockIdx.x;
    int nwg = gx * gy * gridDim.z;
    int chunk = nwg >> 3;
    int f = (lid & 7) * chunk + (lid >> 3);
    int bx = f % gx;
    int by = (f / gx) % gy;
    int bz = f / (gx * gy);

    int tid  = threadIdx.x;
    int m0   = by * 256, n0 = bx * 128;
    int koff = bz * K;
    int lane = tid & 63, wave = tid >> 6;
    int wm = wave >> 1;
    int wn = (wave & 1) * 64;
    int c15 = lane & 15, quad = lane >> 4;

    int rloc  = lane >> 3;
    int sslot = (lane & 7) ^ (rloc & 7);

    auto stageA = [&](int bufo, int g8, int ko) {
        int r0 = g8 * 64 + wave * 8;
        const bf16* g = A + (size_t)(m0 + r0 + rloc) * Kstride + ko + sslot * 8;
        gload_lds16(g, Abase + bufo + r0 * 64);
    };
    auto stageB = [&](int bufo, int g8, int ko) {
        int r0 = g8 * 64 + wave * 8;
        const bf16* g = Bt + (size_t)(n0 + r0 + rloc) * Kstride + ko + sslot * 8;
        gload_lds16(g, Bbase + bufo + r0 * 64);
    };
    auto ldf = [&](const unsigned short* base, int row, int kq) {
        int slot = kq ^ (row & 7);
        return *(const short8*)&base[row * 64 + slot * 8];
    };

    f32x4 acc[4][4] = {};

    int nt = K >> 6;
#pragma unroll
    for (int g8 = 0; g8 < 4; ++g8) stageA(0, g8, koff);
#pragma unroll
    for (int g8 = 0; g8 < 2; ++g8) stageB(0, g8, koff);

    for (int t = 0; t < nt; ++t) {
        int coA = (t & 1) * 16384, noA = coA ^ 16384;
        int coB = (t & 1) * 8192,  noB = coB ^ 8192;
        bool more = (t + 1 < nt);
        int ko1 = koff + (t + 1) * 64;
        const unsigned short* Ac = Abase + coA;
        const unsigned short* Bc = Bbase + coB;

        if (more) {
            stageA(noA, 0, ko1);
            stageA(noA, 1, ko1);
            asm volatile("s_waitcnt vmcnt(2)" ::: "memory");
        } else {
            asm volatile("s_waitcnt vmcnt(0)" ::: "memory");
        }
        __builtin_amdgcn_s_barrier();

#pragma unroll
        for (int p = 0; p < 2; ++p) {
            const int kq0 = p * 4 + quad;
            short8 af[4], bf[4];
#pragma unroll
            for (int i = 0; i < 4; ++i)
                af[i] = ldf(Ac, wm * 64 + i * 16 + c15, kq0);
#pragma unroll
            for (int j = 0; j < 4; ++j)
                bf[j] = ldf(Bc, wn + j * 16 + c15, kq0);
            if (more) {
                if (p == 0) { stageA(noA, 2, ko1); stageA(noA, 3, ko1); }
                if (p == 1) { stageB(noB, 0, ko1); stageB(noB, 1, ko1); }
            }
            __builtin_amdgcn_s_barrier();
            asm volatile("s_waitcnt lgkmcnt(0)" ::: "memory");
            __builtin_amdgcn_sched_barrier(0);
            __builtin_amdgcn_s_setprio(1);
#pragma unroll
            for (int i = 0; i < 4; ++i)
#pragma unroll
                for (int j = 0; j < 4; ++j)
                    acc[i][j] = __builtin_amdgcn_mfma_f32_16x16x32_bf16(
                        af[i], bf[j], acc[i][j], 0, 0, 0);
            __builtin_amdgcn_s_setprio(0);
            __builtin_amdgcn_s_barrier();
        }
    }

    float* dst = (bz == 0) ? outP : part;
#pragma unroll
    for (int i = 0; i < 4; ++i) {
#pragma unroll
        for (int j = 0; j < 4; ++j) {
            int gc = n0 + wn + j * 16 + c15;
#pragma unroll
            for (int r = 0; r < 4; ++r) {
                int gr = m0 + wm * 64 + i * 16 + quad * 4 + r;
                dst[(size_t)gr * N + gc] = acc[i][j][r];
            }
        }
    }
}

// ---------- W2 reduce: out = out + part + bias + resid(bf16) ----------
__global__ __launch_bounds__(256) void w2_reduce(float* __restrict__ out,
                                                 const float* __restrict__ part,
                                                 const float* __restrict__ bias,
                                                 const bf16* __restrict__ resid)
{
    int i = blockIdx.x * 256 + threadIdx.x;
    int col = (i & (D / 4 - 1)) * 4;
    f32x4 a = ((const f32x4*)out)[i];
    f32x4 p = ((const f32x4*)part)[i];
    float4 bb = *(const float4*)(bias + col);
    uint2 rr = ((const uint2*)resid)[i];
    a[0] += p[0] + bb.x + bits2f((unsigned short)(rr.x & 0xffff));
    a[1] += p[1] + bb.y + bits2f((unsigned short)(rr.x >> 16));
    a[2] += p[2] + bb.z + bits2f((unsigned short)(rr.y & 0xffff));
    a[3] += p[3] + bb.w + bits2f((unsigned short)(rr.y >> 16));
    ((f32x4*)out)[i] = a;
}

// ---------- MFMA flash attention (round-8 verified: QBLK=64, grid 1024, T14+T5) ----------
__global__ __launch_bounds__(256) void flash_attn(const bf16* __restrict__ qkv,
                                                  bf16* __restrict__ ctx)
{
    constexpr int KROW = 72;
    constexpr float CSC = 0.18033688011112042f;  // 0.125 * log2(e)
    constexpr float MSH = 12.0f;                 // fixed exp2-domain shift

    __shared__ __align__(16) unsigned short Qs[64 * KROW];
    __shared__ __align__(16) unsigned short Ks[64 * KROW];
    __shared__ __align__(16) unsigned short Vt[64 * KROW];
    unsigned short* Pt = Qs;

    int bx = blockIdx.x;
    int bh = bx & 31;
    int qi = 31 - (bx >> 5);
    int h  = bh & 15, b = bh >> 4;
    int q0 = qi * 64;

    int tid = threadIdx.x, lane = tid & 63, w = tid >> 6;
    int c15 = lane & 15, quad = lane >> 4;

    const bf16* base = qkv + (size_t)b * T * QKVN;

    {
        int row = tid >> 2, qtr = tid & 3;
        const bf16* src = base + (size_t)(q0 + row) * QKVN + h * 64 + qtr * 16;
        unsigned short* dst = &Qs[row * KROW + qtr * 16];
        uint4 v0 = *(const uint4*)(src);
        uint4 v1 = *(const uint4*)(src + 8);
        *(uint4*)(dst)     = v0;
        *(uint4*)(dst + 8) = v1;
    }
    __syncthreads();

    short8 qf[2];
#pragma unroll
    for (int s = 0; s < 2; ++s)
        qf[s] = *(const short8*)&Qs[(w * 16 + c15) * KROW + s * 32 + quad * 8];

    short8 ones;
#pragma unroll
    for (int i = 0; i < 8; ++i) ones[i] = (short)0x3F80;

    f32x4 Ot[4] = {};
    f32x4 lacc  = {};

    int nkt   = q0 / 64 + 1;
    int wqmin = q0 + w * 16;

    int key = tid >> 2, seg = tid & 3;
    int keyp = (tid & 31) * 2, dk0 = (tid >> 5) * 8;

    uint4 kv0, kv1, vv0, vv1;
    {
        const bf16* ksrc = base + (size_t)key * QKVN + D + h * 64 + seg * 16;
        kv0 = *(const uint4*)ksrc;
        kv1 = *(const uint4*)(ksrc + 8);
        const bf16* vsrc = base + (size_t)keyp * QKVN + 2 * D + h * 64 + dk0;
        vv0 = *(const uint4*)vsrc;
        vv1 = *(const uint4*)(vsrc + QKVN);
    }

    for (int kt = 0; kt < nkt; ++kt) {
        int k0 = kt * 64;

        __syncthreads();
        {
            unsigned short* kd = &Ks[key * KROW + seg * 16];
            *(uint4*)kd       = kv0;
            *(uint4*)(kd + 8) = kv1;
            const unsigned short* lo = (const unsigned short*)&vv0;
            const unsigned short* hi = (const unsigned short*)&vv1;
#pragma unroll
            for (int j = 0; j < 8; ++j) {
                unsigned int pk = (unsigned int)lo[j] | ((unsigned int)hi[j] << 16);
                *(unsigned int*)&Vt[(dk0 + j) * KROW + keyp] = pk;
            }
        }
        __syncthreads();

        if (kt + 1 < nkt) {
            int k1 = k0 + 64;
            const bf16* ksrc = base + (size_t)(k1 + key) * QKVN + D + h * 64 + seg * 16;
            kv0 = *(const uint4*)ksrc;
            kv1 = *(const uint4*)(ksrc + 8);
            const bf16* vsrc = base + (size_t)(k1 + keyp) * QKVN + 2 * D + h * 64 + dk0;
            vv0 = *(const uint4*)vsrc;
            vv1 = *(const uint4*)(vsrc + QKVN);
        }

        f32x4 St[4] = {};
        __builtin_amdgcn_s_setprio(1);
#pragma unroll
        for (int s = 0; s < 2; ++s)
#pragma unroll
            for (int ktm = 0; ktm < 4; ++ktm) {
                short8 kf = *(const short8*)&Ks[(ktm * 16 + c15) * KROW + s * 32 + quad * 8];
                St[ktm] = __builtin_amdgcn_mfma_f32_16x16x32_bf16(kf, qf[s], St[ktm], 0, 0, 0);
            }
        __builtin_amdgcn_s_setprio(0);

        if (kt == nkt - 1) {
            int q_g = wqmin + c15;
#pragma unroll
            for (int ktm = 0; ktm < 4; ++ktm) {
                ushort4 pk;
#pragma unroll
                for (int r = 0; r < 4; ++r) {
                    float p = fast_exp2(fmaf(St[ktm][r], CSC, -MSH));
                    if (k0 + ktm * 16 + quad * 4 + r > q_g) p = 0.0f;
                    ((unsigned short*)&pk)[r] = f2bu(p);
                }
                *(ushort4*)&Pt[(w * 16 + c15) * KROW + ktm * 16 + quad * 4] = pk;
            }
        } else {
#pragma unroll
            for (int ktm = 0; ktm < 4; ++ktm) {
                ushort4 pk;
#pragma unroll
                for (int r = 0; r < 4; ++r)
                    ((unsigned short*)&pk)[r] = f2bu(fast_exp2(fmaf(St[ktm][r], CSC, -MSH)));
                *(ushort4*)&Pt[(w * 16 + c15) * KROW + ktm * 16 + quad * 4] = pk;
            }
        }

        __builtin_amdgcn_s_setprio(1);
#pragma unroll
        for (int s = 0; s < 2; ++s) {
            short8 pf = *(const short8*)&Pt[(w * 16 + c15) * KROW + s * 32 + quad * 8];
            lacc = __builtin_amdgcn_mfma_f32_16x16x32_bf16(ones, pf, lacc, 0, 0, 0);
#pragma unroll
            for (int dt = 0; dt < 4; ++dt) {
                short8 vf = *(const short8*)&Vt[(dt * 16 + c15) * KROW + s * 32 + quad * 8];
                Ot[dt] = __builtin_amdgcn_mfma_f32_16x16x32_bf16(vf, pf, Ot[dt], 0, 0, 0);
            }
        }
        __builtin_amdgcn_s_setprio(0);
    }

    {
        float inv = 1.0f / lacc[0];
        int grow = b * T + q0 + w * 16 + c15;
        bf16* dst = ctx + (size_t)grow * D + h * 64 + quad * 4;
#pragma unroll
        for (int dt = 0; dt < 4; ++dt) {
            ushort4 pk;
#pragma unroll
            for (int r = 0; r < 4; ++r)
                ((unsigned short*)&pk)[r] = f2bu(Ot[dt][r] * inv);
            *(ushort4*)(dst + dt * 16) = pk;
        }
    }
}

extern "C" void kernel_launch(void* const* d_in, const int* in_sizes, int n_in,
                              void* d_out, int out_size, void* d_ws, size_t ws_size,
                              hipStream_t stream)
{
    const float* X    = (const float*)d_in[0];
    const float* Wqkv = (const float*)d_in[1];
    const float* bqkv = (const float*)d_in[2];
    const float* Wo   = (const float*)d_in[3];
    const float* bo   = (const float*)d_in[4];
    const float* W1   = (const float*)d_in[5];
    const float* b1   = (const float*)d_in[6];
    const float* W2   = (const float*)d_in[7];
    const float* b2   = (const float*)d_in[8];
    const float* ln1g = (const float*)d_in[9];
    const float* ln1b = (const float*)d_in[10];
    const float* ln2g = (const float*)d_in[11];
    const float* ln2b = (const float*)d_in[12];
    float* out = (float*)d_out;

    // Workspace (peak 72 MiB):
    char* ws = (char*)d_ws;
    bf16* Wqkv_t = (bf16*)(ws + 0);          // [3072][1024]  6 MiB
    bf16* Wo_t   = (bf16*)(ws + 6291456);    // [1024][1024]  2 MiB
    bf16* W1_t   = (bf16*)(ws + 8388608);    // [4096][1024]  8 MiB
    bf16* W2_t   = (bf16*)(ws + 16777216);   // [1024][4096]  8 MiB
    bf16* Xn     = (bf16*)(ws + 25165824);   // 8 MiB; reused by X1 after step 2
    bf16* X1     = Xn;
    bf16* qkv    = (bf16*)(ws + 33554432);   // 24 MiB; first 8 MiB reused by Xn2 after attn
    bf16* Xn2    = (bf16*)(ws + 33554432);
    bf16* ctx    = (bf16*)(ws + 58720256);   // 8 MiB
    bf16* mid    = (bf16*)(ws + 41943040);   // 32 MiB; ends at 72 MiB
    float* W2part = (float*)(ws + 0);        // [4096][1024] f32, 16 MiB (weights dead)

    transpose_cast<<<dim3(QKVN / 32, D / 32), 256, 0, stream>>>(Wqkv, Wqkv_t, D, QKVN);
    transpose_cast<<<dim3(D / 32, D / 32), 256, 0, stream>>>(Wo, Wo_t, D, D);
    transpose_cast<<<dim3(FFNN / 32, D / 32), 256, 0, stream>>>(W1, W1_t, D, FFNN);
    transpose_cast<<<dim3(D / 32, FFNN / 32), 256, 0, stream>>>(W2, W2_t, FFNN, D);

    ln_kernel<float><<<ROWS, 256, 0, stream>>>(X, ln1g, ln1b, Xn);
    // QKV: 8-phase template, BN=192 -> grid 16x16 = 256 blocks = 1/CU (112 KiB LDS)
    gemm256<0, 192><<<dim3(QKVN / 192, ROWS / 256), 512, 114688, stream>>>(
        Xn, Wqkv_t, bqkv, qkv, ROWS, QKVN, D);
    // attn: round-8 verified version (QBLK=64, 1024 blocks x 256 threads)
    flash_attn<<<1024, 256, 0, stream>>>(qkv, ctx);
    mfma_gemm<64, 0, 2, 0, 0><<<dim3(D / 128, ROWS / 64), 256, 0, stream>>>(
        ctx, Wo_t, bo, X, X1, nullptr, ROWS, D, D, D);
    ln_kernel<bf16><<<ROWS, 256, 0, stream>>>(X1, ln2g, ln2b, Xn2);
    // W1: 8-phase 256^2 template — verified round 7
    gemm256<1, 256><<<dim3(FFNN / 256, ROWS / 256), 512, 131072, stream>>>(
        Xn2, W1_t, b1, mid, ROWS, FFNN, D);
    // W2: 8-phase 256x128 split-K=2 — verified round 8
    gemm_w2<<<dim3(D / 128, ROWS / 256, 2), 512, 98304, stream>>>(
        mid, W2_t, out, W2part, ROWS, D, FFNN / 2, FFNN);
    w2_reduce<<<ROWS * D / 4 / 256, 256, 0, stream>>>(out, W2part, b2, X1);
}